// Round 4
// baseline (1124.905 us; speedup 1.0000x reference)
//
#include <hip/hip_runtime.h>
#include <cstdint>
#include <cstddef>

// ---------- problem constants ----------
#define DIM      1024
#define GROUP    16
#define LORA     20
#define NLAYERS  18
#define NBLOCKS  6
#define BATCH    8192
#define EPS      1e-5f

typedef __bf16 bf16_8 __attribute__((ext_vector_type(8)));
typedef __bf16 bf16_4 __attribute__((ext_vector_type(4)));
typedef float  f32x4  __attribute__((ext_vector_type(4)));

// ---------------------------------------------------------------------------
// Weight prep: W_total[l][o][k] = qw*scale + sum_r B[o][r]*A[r][k], split bf16
// hi/lo. A-slice staged in LDS.
// ---------------------------------------------------------------------------
__global__ __launch_bounds__(256) void wprep_kernel(
    const int* __restrict__ qw, const float* __restrict__ sc,
    const float* __restrict__ la, const float* __restrict__ lb,
    __bf16* __restrict__ whi, __bf16* __restrict__ wlo) {
  const int l  = blockIdx.x >> 5;
  const int og = (blockIdx.x >> 1) & 15;
  const int cg = blockIdx.x & 1;
  const int tid = threadIdx.x;

  __shared__ float As[LORA * 512];
  __shared__ float Bs[64 * LORA];

  const float* Abase = la + (size_t)l * LORA * DIM + cg * 512;
#pragma unroll
  for (int i = 0; i < 10; ++i) {
    const int f4 = i * 256 + tid;
    const int j  = f4 >> 7;
    const int c4 = f4 & 127;
    ((float4*)As)[f4] = *(const float4*)(Abase + (size_t)j * DIM + c4 * 4);
  }
  const float* Bbase = lb + ((size_t)l * DIM + og * 64) * LORA;
#pragma unroll
  for (int i = 0; i < 5; ++i) Bs[i * 256 + tid] = Bbase[i * 256 + tid];
  __syncthreads();

  const int colg = (tid & 127) * 4;
  const int rh   = tid >> 7;
#pragma unroll 1
  for (int s = 0; s < 32; ++s) {
    const int r    = rh * 32 + s;
    const int orow = og * 64 + r;
    const size_t wbase = ((size_t)l * DIM + orow) * DIM + cg * 512 + colg;
    const int4 q4 = *(const int4*)&qw[wbase];
    const float sv = sc[((size_t)l * DIM + orow) * (DIM / GROUP) + ((cg * 512 + colg) >> 4)];
    float a0 = q4.x * sv, a1 = q4.y * sv, a2 = q4.z * sv, a3 = q4.w * sv;
    const float* Br = &Bs[r * LORA];
#pragma unroll
    for (int j = 0; j < LORA; ++j) {
      const float bj = Br[j];
      const float* Aj = &As[j * 512 + colg];
      a0 += bj * Aj[0]; a1 += bj * Aj[1]; a2 += bj * Aj[2]; a3 += bj * Aj[3];
    }
    const __bf16 h0 = (__bf16)a0, h1 = (__bf16)a1, h2 = (__bf16)a2, h3 = (__bf16)a3;
    const bf16_4 hv = {h0, h1, h2, h3};
    const bf16_4 lv = {(__bf16)(a0 - (float)h0), (__bf16)(a1 - (float)h1),
                       (__bf16)(a2 - (float)h2), (__bf16)(a3 - (float)h3)};
    *(bf16_4*)&whi[wbase] = hv;
    *(bf16_4*)&wlo[wbase] = lv;
  }
}

// ---------------------------------------------------------------------------
// x prep: f32 -> bf16 hi/lo split
// ---------------------------------------------------------------------------
__global__ __launch_bounds__(256) void xprep_kernel(
    const float* __restrict__ x, __bf16* __restrict__ hi, __bf16* __restrict__ lo) {
  const size_t i = (size_t)blockIdx.x * 256 + threadIdx.x;
  const float4 v = ((const float4*)x)[i];
  const __bf16 h0 = (__bf16)v.x, h1 = (__bf16)v.y, h2 = (__bf16)v.z, h3 = (__bf16)v.w;
  const bf16_4 hv = {h0, h1, h2, h3};
  const bf16_4 lv = {(__bf16)(v.x - (float)h0), (__bf16)(v.y - (float)h1),
                     (__bf16)(v.z - (float)h2), (__bf16)(v.w - (float)h3)};
  ((bf16_4*)hi)[i] = hv;
  ((bf16_4*)lo)[i] = lv;
}

// ---------------------------------------------------------------------------
// 3-pass split-bf16 GEMM, 4-phase schedule (m201 mini-port).
// Tile: 256 batch x 128 feat, BK=32. 8 waves = 2 feat-groups x 4 batch-groups.
// LDS buffer (48KB): Xh[256x32] | Xl | Wh[128x32] | Wl (linear — b128 frag
// reads over a contiguous region have layout-invariant bank cost; swizzle
// proven useless in R3). 3 buffers, depth-2 in-flight, vmcnt(6) once/k-step.
// Per k-step: 4 phases {stage-subset || ds_read frags} -> s_barrier ->
// setprio(1) 12 MFMA setprio(0) -> s_barrier.  Waves slip between barriers:
// ds_read/stage of one wave overlaps MFMA of another (T3+T4+T5).
// ---------------------------------------------------------------------------
#define BUF_ELEMS 24576   // 48 KB in bf16 elems
#define OFF_XL    8192
#define OFF_WH    16384
#define OFF_WL    20480

template <int NISSUE>
__device__ __forceinline__ void stage32(const __bf16* __restrict__ g, int row0, int k0,
                                        __bf16* lds, int tid) {
  const int wvbase = (tid >> 6) * 512;     // elems: wave-uniform LDS base
#pragma unroll
  for (int i = 0; i < NISSUE; ++i) {
    const int D = i * 8192 + tid * 16;     // linear byte in region
    const int r  = D >> 6;                 // 64 B per row
    const int ce = (D & 63) >> 1;
    const __bf16* gp = g + (size_t)(row0 + r) * DIM + k0 + ce;
    __builtin_amdgcn_global_load_lds(
        (const __attribute__((address_space(1))) void*)gp,
        (__attribute__((address_space(3))) void*)(lds + i * 4096 + wvbase), 16, 0, 0);
  }
}

template <bool RELU_SPLIT>
__global__ __launch_bounds__(512, 1) void gemm3_kernel(
    const __bf16* __restrict__ Xh, const __bf16* __restrict__ Xl,
    const __bf16* __restrict__ Wh, const __bf16* __restrict__ Wl,
    const float* __restrict__ bias,
    __bf16* __restrict__ Oh, __bf16* __restrict__ Ol,
    const float* __restrict__ Hin, float* __restrict__ Sout) {
  extern __shared__ __bf16 smem[];         // 3 * 24576 elems = 144 KB

  const int tid  = threadIdx.x;
  const int lane = tid & 63;
  const int wv   = tid >> 6;
  const int wm   = wv >> 2;                // feature group (2 x 64)
  const int wn2  = wv & 3;                 // batch group   (4 x 64)
  const int s  = ((blockIdx.x & 7) << 5) + (blockIdx.x >> 3);  // XCD-chunked
  const int tm = s >> 3, tn = s & 7;
  const int rowX = tm * 256, rowW = tn * 128;

  const int lr   = lane & 15;
  const int slot = lane >> 4;

  int offX[4], offW[4];
#pragma unroll
  for (int n = 0; n < 4; ++n) offX[n] = (wn2 * 64 + n * 16 + lr) * 32 + slot * 8;
#pragma unroll
  for (int m = 0; m < 4; ++m) offW[m] = OFF_WH + (wm * 64 + m * 16 + lr) * 32 + slot * 8;

  f32x4 acc[4][4];
#pragma unroll
  for (int m = 0; m < 4; ++m)
#pragma unroll
    for (int n = 0; n < 4; ++n) acc[m][n] = f32x4{0.f, 0.f, 0.f, 0.f};

  bf16_8 x_h[4], x_l[4];

  // one phase: MFMA row m of the acc grid (12 MFMAs)
  auto mfma_row = [&](int m, bf16_8 w_h, bf16_8 w_l) {
    __builtin_amdgcn_s_setprio(1);
#pragma unroll
    for (int n = 0; n < 4; ++n) {
      acc[m][n] = __builtin_amdgcn_mfma_f32_16x16x32_bf16(w_h, x_h[n], acc[m][n], 0, 0, 0);
      acc[m][n] = __builtin_amdgcn_mfma_f32_16x16x32_bf16(w_h, x_l[n], acc[m][n], 0, 0, 0);
      acc[m][n] = __builtin_amdgcn_mfma_f32_16x16x32_bf16(w_l, x_h[n], acc[m][n], 0, 0, 0);
    }
    __builtin_amdgcn_s_setprio(0);
  };

  // monolithic compute for the 2 tail k-steps
  auto compute_tile = [&](const __bf16* buf) {
#pragma unroll
    for (int n = 0; n < 4; ++n) {
      x_h[n] = *(const bf16_8*)&buf[offX[n]];
      x_l[n] = *(const bf16_8*)&buf[offX[n] + OFF_XL];
    }
#pragma unroll
    for (int m = 0; m < 4; ++m) {
      const bf16_8 w_h = *(const bf16_8*)&buf[offW[m]];
      const bf16_8 w_l = *(const bf16_8*)&buf[offW[m] + (OFF_WL - OFF_WH)];
      mfma_row(m, w_h, w_l);
    }
  };

  // prologue: tiles 0,1 in flight; wait tile 0 (6 newest = tile 1 stay out)
  {
    __bf16* b0 = smem;
    __bf16* b1 = smem + BUF_ELEMS;
    stage32<2>(Xh, rowX, 0, b0, tid);
    stage32<2>(Xl, rowX, 0, b0 + OFF_XL, tid);
    stage32<1>(Wh, rowW, 0, b0 + OFF_WH, tid);
    stage32<1>(Wl, rowW, 0, b0 + OFF_WL, tid);
    stage32<2>(Xh, rowX, 32, b1, tid);
    stage32<2>(Xl, rowX, 32, b1 + OFF_XL, tid);
    stage32<1>(Wh, rowW, 32, b1 + OFF_WH, tid);
    stage32<1>(Wl, rowW, 32, b1 + OFF_WL, tid);
  }
  asm volatile("s_waitcnt vmcnt(6)" ::: "memory");
  __builtin_amdgcn_s_barrier();

  int cur = 0;
#pragma unroll 1
  for (int kt = 0; kt < 30; ++kt) {
    int pb = cur + 2; if (pb >= 3) pb -= 3;
    __bf16* sb = smem + pb * BUF_ELEMS;
    const __bf16* buf = smem + cur * BUF_ELEMS;
    const int k2 = (kt + 2) * 32;

    // ---- phase 0: stage Xh(2) | read x frags + w0 | MFMA m=0
    stage32<2>(Xh, rowX, k2, sb, tid);
#pragma unroll
    for (int n = 0; n < 4; ++n) {
      x_h[n] = *(const bf16_8*)&buf[offX[n]];
      x_l[n] = *(const bf16_8*)&buf[offX[n] + OFF_XL];
    }
    {
      const bf16_8 w_h = *(const bf16_8*)&buf[offW[0]];
      const bf16_8 w_l = *(const bf16_8*)&buf[offW[0] + (OFF_WL - OFF_WH)];
      __builtin_amdgcn_s_barrier();
      mfma_row(0, w_h, w_l);
      __builtin_amdgcn_s_barrier();
    }
    // ---- phase 1: stage Xl(2) | read w1 | MFMA m=1
    stage32<2>(Xl, rowX, k2, sb + OFF_XL, tid);
    {
      const bf16_8 w_h = *(const bf16_8*)&buf[offW[1]];
      const bf16_8 w_l = *(const bf16_8*)&buf[offW[1] + (OFF_WL - OFF_WH)];
      __builtin_amdgcn_s_barrier();
      mfma_row(1, w_h, w_l);
      __builtin_amdgcn_s_barrier();
    }
    // ---- phase 2: stage Wh(1) | read w2 | MFMA m=2
    stage32<1>(Wh, rowW, k2, sb + OFF_WH, tid);
    {
      const bf16_8 w_h = *(const bf16_8*)&buf[offW[2]];
      const bf16_8 w_l = *(const bf16_8*)&buf[offW[2] + (OFF_WL - OFF_WH)];
      __builtin_amdgcn_s_barrier();
      mfma_row(2, w_h, w_l);
      __builtin_amdgcn_s_barrier();
    }
    // ---- phase 3: stage Wl(1) | read w3 | vmcnt(6) | MFMA m=3
    stage32<1>(Wl, rowW, k2, sb + OFF_WL, tid);
    {
      const bf16_8 w_h = *(const bf16_8*)&buf[offW[3]];
      const bf16_8 w_l = *(const bf16_8*)&buf[offW[3] + (OFF_WL - OFF_WH)];
      // drain tile kt+1's 6 loads (oldest); kt+2's 6 newest stay in flight
      asm volatile("s_waitcnt vmcnt(6)" ::: "memory");
      __builtin_amdgcn_s_barrier();
      mfma_row(3, w_h, w_l);
      __builtin_amdgcn_s_barrier();
    }
    ++cur; if (cur == 3) cur = 0;
  }
  // tail: kt=30 (tile ready), then wait rest and kt=31
  compute_tile(smem + cur * BUF_ELEMS);
  asm volatile("s_waitcnt vmcnt(0)" ::: "memory");
  __builtin_amdgcn_s_barrier();
  ++cur; if (cur == 3) cur = 0;
  compute_tile(smem + cur * BUF_ELEMS);

  // epilogue: D reg-quad = 4 consecutive features of one batch row
  const int g4 = slot * 4;
#pragma unroll
  for (int m = 0; m < 4; ++m) {
    const int feat = tn * 128 + wm * 64 + m * 16 + g4;
    const float4 bv = *(const float4*)&bias[feat];
#pragma unroll
    for (int n = 0; n < 4; ++n) {
      const int nb = tm * 256 + wn2 * 64 + n * 16 + lr;
      const size_t base = (size_t)nb * DIM + feat;
      float v0 = acc[m][n][0] + bv.x;
      float v1 = acc[m][n][1] + bv.y;
      float v2 = acc[m][n][2] + bv.z;
      float v3 = acc[m][n][3] + bv.w;
      if constexpr (RELU_SPLIT) {
        v0 = fmaxf(v0, 0.f); v1 = fmaxf(v1, 0.f);
        v2 = fmaxf(v2, 0.f); v3 = fmaxf(v3, 0.f);
        const __bf16 h0 = (__bf16)v0, h1 = (__bf16)v1, h2 = (__bf16)v2, h3 = (__bf16)v3;
        const bf16_4 hv = {h0, h1, h2, h3};
        const bf16_4 lv = {(__bf16)(v0 - (float)h0), (__bf16)(v1 - (float)h1),
                           (__bf16)(v2 - (float)h2), (__bf16)(v3 - (float)h3)};
        *(bf16_4*)&Oh[base] = hv;
        *(bf16_4*)&Ol[base] = lv;
      } else {
        const float4 h = *(const float4*)&Hin[base];
        *(float4*)&Sout[base] = float4{v0 + h.x, v1 + h.y, v2 + h.z, v3 + h.w};
      }
    }
  }
}

// ---------------------------------------------------------------------------
// Row LayerNorm: H = LN(S)*w+b (f32) plus bf16 hi/lo split of H.
// ---------------------------------------------------------------------------
__global__ __launch_bounds__(256) void ln_kernel(
    const float* __restrict__ S, const float* __restrict__ w,
    const float* __restrict__ b, float* __restrict__ H,
    __bf16* __restrict__ phi, __bf16* __restrict__ plo) {
  const int row = blockIdx.x;
  const int tid = threadIdx.x;
  const int lane = tid & 63;
  const int wv = tid >> 6;
  const float4 v = ((const float4*)(S + (size_t)row * DIM))[tid];

  float s = v.x + v.y + v.z + v.w;
#pragma unroll
  for (int m = 32; m; m >>= 1) s += __shfl_xor(s, m, 64);
  __shared__ float red[8];
  if (lane == 0) red[wv] = s;
  __syncthreads();
  const float mean = (red[0] + red[1] + red[2] + red[3]) * (1.f / DIM);

  const float d0 = v.x - mean, d1 = v.y - mean, d2 = v.z - mean, d3 = v.w - mean;
  float q = d0 * d0 + d1 * d1 + d2 * d2 + d3 * d3;
#pragma unroll
  for (int m = 32; m; m >>= 1) q += __shfl_xor(q, m, 64);
  if (lane == 0) red[4 + wv] = q;
  __syncthreads();
  const float var = (red[4] + red[5] + red[6] + red[7]) * (1.f / DIM);
  const float inv = 1.f / sqrtf(var + EPS);

  const float4 wv4 = ((const float4*)w)[tid];
  const float4 bv4 = ((const float4*)b)[tid];
  const float y0 = d0 * inv * wv4.x + bv4.x;
  const float y1 = d1 * inv * wv4.y + bv4.y;
  const float y2 = d2 * inv * wv4.z + bv4.z;
  const float y3 = d3 * inv * wv4.w + bv4.w;

  ((float4*)(H + (size_t)row * DIM))[tid] = float4{y0, y1, y2, y3};
  const __bf16 h0 = (__bf16)y0, h1 = (__bf16)y1, h2 = (__bf16)y2, h3 = (__bf16)y3;
  const bf16_4 hv = {h0, h1, h2, h3};
  const bf16_4 lv = {(__bf16)(y0 - (float)h0), (__bf16)(y1 - (float)h1),
                     (__bf16)(y2 - (float)h2), (__bf16)(y3 - (float)h3)};
  const size_t base4 = (size_t)row * (DIM / 4) + tid;
  ((bf16_4*)phi)[base4] = hv;
  ((bf16_4*)plo)[base4] = lv;
}

// ---------------------------------------------------------------------------
// launch
// ---------------------------------------------------------------------------
extern "C" void kernel_launch(void* const* d_in, const int* in_sizes, int n_in,
                              void* d_out, int out_size, void* d_ws, size_t ws_size,
                              hipStream_t stream) {
  const float* x   = (const float*)d_in[0];
  const int*   qw  = (const int*)d_in[1];
  const float* sc  = (const float*)d_in[2];
  const float* bias= (const float*)d_in[3];
  const float* la  = (const float*)d_in[4];
  const float* lb  = (const float*)d_in[5];
  const float* lnw = (const float*)d_in[6];
  const float* lnb = (const float*)d_in[7];
  float* out = (float*)d_out;
  char* ws = (char*)d_ws;

  __bf16* WHI = (__bf16*)(ws);
  __bf16* WLO = (__bf16*)(ws + 37748736);
  __bf16* P0H = (__bf16*)(ws + 75497472);
  __bf16* P0L = (__bf16*)(ws + 92274688);
  __bf16* P1H = (__bf16*)(ws + 109051904);
  __bf16* P1L = (__bf16*)(ws + 125829120);
  float*  Sb  = (float*)(ws + 109051904);   // aliases P1 (dead when Sb live)
  float*  Hb  = (float*)(ws + 142606336);
  (void)ws_size; (void)in_sizes; (void)n_in; (void)out_size;

  xprep_kernel<<<BATCH * DIM / (256 * 4), 256, 0, stream>>>(x, P0H, P0L);
  wprep_kernel<<<NLAYERS * 32, 256, 0, stream>>>(qw, sc, la, lb, WHI, WLO);

  const dim3 ggrid(BATCH / 256 * (DIM / 128));  // 32 * 8 = 256
  const size_t smem_bytes = 3 * BUF_ELEMS * sizeof(__bf16);  // 147456
  for (int blk = 0; blk < NBLOCKS; ++blk) {
    const int li = blk * 3;
    const size_t w0 = (size_t)li * DIM * DIM;
    const size_t w1 = (size_t)(li + 1) * DIM * DIM;
    const size_t w2 = (size_t)(li + 2) * DIM * DIM;

    gemm3_kernel<true><<<ggrid, 512, smem_bytes, stream>>>(
        P0H, P0L, WHI + w0, WLO + w0, bias + (size_t)li * DIM,
        P1H, P1L, nullptr, nullptr);
    gemm3_kernel<true><<<ggrid, 512, smem_bytes, stream>>>(
        P1H, P1L, WHI + w1, WLO + w1, bias + (size_t)(li + 1) * DIM,
        P0H, P0L, nullptr, nullptr);
    const float* hin = (blk == 0) ? x : Hb;
    float* sout = (blk == NBLOCKS - 1) ? out : Sb;
    gemm3_kernel<false><<<ggrid, 512, smem_bytes, stream>>>(
        P0H, P0L, WHI + w2, WLO + w2, bias + (size_t)(li + 2) * DIM,
        nullptr, nullptr, hin, sout);
    if (blk < NBLOCKS - 1) {
      ln_kernel<<<BATCH, 256, 0, stream>>>(Sb, lnw + (size_t)blk * DIM,
                                           lnb + (size_t)blk * DIM, Hb, P0H, P0L);
    }
  }
}

// Round 5
// 828.801 us; speedup vs baseline: 1.3573x; 1.3573x over previous
//
#include <hip/hip_runtime.h>
#include <cstdint>
#include <cstddef>

// ---------- problem constants ----------
#define DIM      1024
#define GROUP    16
#define LORA     20
#define NLAYERS  18
#define NBLOCKS  6
#define BATCH    8192
#define EPS      1e-5f

typedef __bf16 bf16_8 __attribute__((ext_vector_type(8)));
typedef __bf16 bf16_4 __attribute__((ext_vector_type(4)));
typedef float  f32x4  __attribute__((ext_vector_type(4)));

// ---------------------------------------------------------------------------
// Weight prep: W_total[l][o][k] = qw*scale + sum_r B[o][r]*A[r][k], split bf16
// hi/lo (W keeps ~16 mantissa bits across the two terms). A-slice in LDS.
// ---------------------------------------------------------------------------
__global__ __launch_bounds__(256) void wprep_kernel(
    const int* __restrict__ qw, const float* __restrict__ sc,
    const float* __restrict__ la, const float* __restrict__ lb,
    __bf16* __restrict__ whi, __bf16* __restrict__ wlo) {
  const int l  = blockIdx.x >> 5;
  const int og = (blockIdx.x >> 1) & 15;
  const int cg = blockIdx.x & 1;
  const int tid = threadIdx.x;

  __shared__ float As[LORA * 512];
  __shared__ float Bs[64 * LORA];

  const float* Abase = la + (size_t)l * LORA * DIM + cg * 512;
#pragma unroll
  for (int i = 0; i < 10; ++i) {
    const int f4 = i * 256 + tid;
    const int j  = f4 >> 7;
    const int c4 = f4 & 127;
    ((float4*)As)[f4] = *(const float4*)(Abase + (size_t)j * DIM + c4 * 4);
  }
  const float* Bbase = lb + ((size_t)l * DIM + og * 64) * LORA;
#pragma unroll
  for (int i = 0; i < 5; ++i) Bs[i * 256 + tid] = Bbase[i * 256 + tid];
  __syncthreads();

  const int colg = (tid & 127) * 4;
  const int rh   = tid >> 7;
#pragma unroll 1
  for (int s = 0; s < 32; ++s) {
    const int r    = rh * 32 + s;
    const int orow = og * 64 + r;
    const size_t wbase = ((size_t)l * DIM + orow) * DIM + cg * 512 + colg;
    const int4 q4 = *(const int4*)&qw[wbase];
    const float sv = sc[((size_t)l * DIM + orow) * (DIM / GROUP) + ((cg * 512 + colg) >> 4)];
    float a0 = q4.x * sv, a1 = q4.y * sv, a2 = q4.z * sv, a3 = q4.w * sv;
    const float* Br = &Bs[r * LORA];
#pragma unroll
    for (int j = 0; j < LORA; ++j) {
      const float bj = Br[j];
      const float* Aj = &As[j * 512 + colg];
      a0 += bj * Aj[0]; a1 += bj * Aj[1]; a2 += bj * Aj[2]; a3 += bj * Aj[3];
    }
    const __bf16 h0 = (__bf16)a0, h1 = (__bf16)a1, h2 = (__bf16)a2, h3 = (__bf16)a3;
    const bf16_4 hv = {h0, h1, h2, h3};
    const bf16_4 lv = {(__bf16)(a0 - (float)h0), (__bf16)(a1 - (float)h1),
                       (__bf16)(a2 - (float)h2), (__bf16)(a3 - (float)h3)};
    *(bf16_4*)&whi[wbase] = hv;
    *(bf16_4*)&wlo[wbase] = lv;
  }
}

// ---------------------------------------------------------------------------
// x prep: f32 -> single bf16
// ---------------------------------------------------------------------------
__global__ __launch_bounds__(256) void xprep_kernel(
    const float* __restrict__ x, __bf16* __restrict__ hi) {
  const size_t i = (size_t)blockIdx.x * 256 + threadIdx.x;
  const float4 v = ((const float4*)x)[i];
  const bf16_4 hv = {(__bf16)v.x, (__bf16)v.y, (__bf16)v.z, (__bf16)v.w};
  ((bf16_4*)hi)[i] = hv;
}

// ---------------------------------------------------------------------------
// 2-pass split-W bf16 GEMM (x single bf16; W = Wh + Wl).
// Tile 128x128, BK=32, 256 thr (4 waves 2x2), static 48KB LDS (2 bufs x 24KB)
// -> 3 blocks/CU capacity, grid 512 = 2 resident/CU: cross-block TLP hides
// the stage/drain stall (m97/m114 regime). Simple 2-phase loop.
// MFMA A=W-frag, B=x-frag -> D reg-quad = 4 consecutive features of one batch
// row -> vectorized epilogue stores.
// ---------------------------------------------------------------------------
#define GBUF    12288   // elems per buffer (24 KB)
#define GOFF_WH 4096
#define GOFF_WL 8192

__device__ __forceinline__ void stageR(const __bf16* __restrict__ g, int row0, int k0,
                                       __bf16* lds, int tid) {
  const int wvbase = (tid >> 6) * 512;     // elems: wave-uniform LDS base
#pragma unroll
  for (int i = 0; i < 2; ++i) {
    const int D = i * 4096 + tid * 16;     // byte in 8KB region
    const int r  = D >> 6;                 // 64 B per row (BK=32 bf16)
    const int ce = (D & 63) >> 1;
    const __bf16* gp = g + (size_t)(row0 + r) * DIM + k0 + ce;
    __builtin_amdgcn_global_load_lds(
        (const __attribute__((address_space(1))) void*)gp,
        (__attribute__((address_space(3))) void*)(lds + i * 2048 + wvbase), 16, 0, 0);
  }
}

template <bool RELU_OUT>
__global__ __launch_bounds__(256, 3) void gemm2_kernel(
    const __bf16* __restrict__ X, const __bf16* __restrict__ Wh,
    const __bf16* __restrict__ Wl, const float* __restrict__ bias,
    __bf16* __restrict__ Oh,
    const float* __restrict__ Hin, float* __restrict__ Sout) {
  __shared__ __bf16 smem[2 * GBUF];        // 48 KB

  const int tid  = threadIdx.x;
  const int lane = tid & 63;
  const int wv   = tid >> 6;
  const int wm   = wv >> 1;                // feature half (2 x 64)
  const int wn   = wv & 1;                 // batch half   (2 x 64)
  // XCD-chunked swizzle: 512 wg, 8 XCDs, 64-chunks (bijective, 512%8==0)
  const int s  = ((blockIdx.x & 7) << 6) + (blockIdx.x >> 3);
  const int tm = s >> 3, tn = s & 7;
  const int rowX = tm * 128, rowW = tn * 128;

  const int lr   = lane & 15;
  const int slot = lane >> 4;

  int offX[4], offW[4];
#pragma unroll
  for (int n = 0; n < 4; ++n) offX[n] = (wn * 64 + n * 16 + lr) * 32 + slot * 8;
#pragma unroll
  for (int m = 0; m < 4; ++m) offW[m] = GOFF_WH + (wm * 64 + m * 16 + lr) * 32 + slot * 8;

  f32x4 acc[4][4];
#pragma unroll
  for (int m = 0; m < 4; ++m)
#pragma unroll
    for (int n = 0; n < 4; ++n) acc[m][n] = f32x4{0.f, 0.f, 0.f, 0.f};

  auto stage_tile = [&](int k0, __bf16* sb) {
    stageR(X,  rowX, k0, sb, tid);
    stageR(Wh, rowW, k0, sb + GOFF_WH, tid);
    stageR(Wl, rowW, k0, sb + GOFF_WL, tid);
  };

  auto compute_tile = [&](const __bf16* buf) {
    bf16_8 xf[4];
#pragma unroll
    for (int n = 0; n < 4; ++n) xf[n] = *(const bf16_8*)&buf[offX[n]];
#pragma unroll
    for (int m = 0; m < 4; ++m) {
      const bf16_8 w_h = *(const bf16_8*)&buf[offW[m]];
      const bf16_8 w_l = *(const bf16_8*)&buf[offW[m] + (GOFF_WL - GOFF_WH)];
#pragma unroll
      for (int n = 0; n < 4; ++n) {
        acc[m][n] = __builtin_amdgcn_mfma_f32_16x16x32_bf16(w_h, xf[n], acc[m][n], 0, 0, 0);
        acc[m][n] = __builtin_amdgcn_mfma_f32_16x16x32_bf16(w_l, xf[n], acc[m][n], 0, 0, 0);
      }
    }
  };

  stage_tile(0, smem);
  __syncthreads();

  int cur = 0;
#pragma unroll 1
  for (int kt = 0; kt < 31; ++kt) {
    stage_tile((kt + 1) * 32, smem + (cur ^ 1) * GBUF);
    compute_tile(smem + cur * GBUF);
    __syncthreads();      // drains vmcnt(0): next buffer ready; cur reusable
    cur ^= 1;
  }
  compute_tile(smem + cur * GBUF);

  // epilogue: D reg-quad = 4 consecutive features of one batch row
  const int g4 = slot * 4;
#pragma unroll
  for (int m = 0; m < 4; ++m) {
    const int feat = tn * 128 + wm * 64 + m * 16 + g4;
    const float4 bv = *(const float4*)&bias[feat];
#pragma unroll
    for (int n = 0; n < 4; ++n) {
      const int nb = tm * 128 + wn * 64 + n * 16 + lr;
      const size_t base = (size_t)nb * DIM + feat;
      float v0 = acc[m][n][0] + bv.x;
      float v1 = acc[m][n][1] + bv.y;
      float v2 = acc[m][n][2] + bv.z;
      float v3 = acc[m][n][3] + bv.w;
      if constexpr (RELU_OUT) {
        const bf16_4 hv = {(__bf16)fmaxf(v0, 0.f), (__bf16)fmaxf(v1, 0.f),
                           (__bf16)fmaxf(v2, 0.f), (__bf16)fmaxf(v3, 0.f)};
        *(bf16_4*)&Oh[base] = hv;
      } else {
        const float4 h = *(const float4*)&Hin[base];
        *(float4*)&Sout[base] = float4{v0 + h.x, v1 + h.y, v2 + h.z, v3 + h.w};
      }
    }
  }
}

// ---------------------------------------------------------------------------
// Row LayerNorm: H = LN(S)*w+b (f32) plus bf16 cast (next block's GEMM input).
// ---------------------------------------------------------------------------
__global__ __launch_bounds__(256) void ln_kernel(
    const float* __restrict__ S, const float* __restrict__ w,
    const float* __restrict__ b, float* __restrict__ H,
    __bf16* __restrict__ phi) {
  const int row = blockIdx.x;
  const int tid = threadIdx.x;
  const int lane = tid & 63;
  const int wv = tid >> 6;
  const float4 v = ((const float4*)(S + (size_t)row * DIM))[tid];

  float s = v.x + v.y + v.z + v.w;
#pragma unroll
  for (int m = 32; m; m >>= 1) s += __shfl_xor(s, m, 64);
  __shared__ float red[8];
  if (lane == 0) red[wv] = s;
  __syncthreads();
  const float mean = (red[0] + red[1] + red[2] + red[3]) * (1.f / DIM);

  const float d0 = v.x - mean, d1 = v.y - mean, d2 = v.z - mean, d3 = v.w - mean;
  float q = d0 * d0 + d1 * d1 + d2 * d2 + d3 * d3;
#pragma unroll
  for (int m = 32; m; m >>= 1) q += __shfl_xor(q, m, 64);
  if (lane == 0) red[4 + wv] = q;
  __syncthreads();
  const float var = (red[4] + red[5] + red[6] + red[7]) * (1.f / DIM);
  const float inv = 1.f / sqrtf(var + EPS);

  const float4 wv4 = ((const float4*)w)[tid];
  const float4 bv4 = ((const float4*)b)[tid];
  const float y0 = d0 * inv * wv4.x + bv4.x;
  const float y1 = d1 * inv * wv4.y + bv4.y;
  const float y2 = d2 * inv * wv4.z + bv4.z;
  const float y3 = d3 * inv * wv4.w + bv4.w;

  ((float4*)(H + (size_t)row * DIM))[tid] = float4{y0, y1, y2, y3};
  const bf16_4 hv = {(__bf16)y0, (__bf16)y1, (__bf16)y2, (__bf16)y3};
  ((bf16_4*)phi)[(size_t)row * (DIM / 4) + tid] = hv;
}

// ---------------------------------------------------------------------------
// launch
// ---------------------------------------------------------------------------
extern "C" void kernel_launch(void* const* d_in, const int* in_sizes, int n_in,
                              void* d_out, int out_size, void* d_ws, size_t ws_size,
                              hipStream_t stream) {
  const float* x   = (const float*)d_in[0];
  const int*   qw  = (const int*)d_in[1];
  const float* sc  = (const float*)d_in[2];
  const float* bias= (const float*)d_in[3];
  const float* la  = (const float*)d_in[4];
  const float* lb  = (const float*)d_in[5];
  const float* lnw = (const float*)d_in[6];
  const float* lnb = (const float*)d_in[7];
  float* out = (float*)d_out;
  char* ws = (char*)d_ws;

  // workspace layout (bytes): WHI 36M | WLO 36M | X0 16M | X1 16M | Sb 32M | Hb 32M
  __bf16* WHI = (__bf16*)(ws);
  __bf16* WLO = (__bf16*)(ws + 37748736);
  __bf16* X0  = (__bf16*)(ws + 75497472);
  __bf16* X1  = (__bf16*)(ws + 92274688);
  float*  Sb  = (float*)(ws + 109051904);
  float*  Hb  = (float*)(ws + 142606336);
  (void)ws_size; (void)in_sizes; (void)n_in; (void)out_size;

  xprep_kernel<<<BATCH * DIM / (256 * 4), 256, 0, stream>>>(x, X0);
  wprep_kernel<<<NLAYERS * 32, 256, 0, stream>>>(qw, sc, la, lb, WHI, WLO);

  const dim3 ggrid(BATCH / 128 * (DIM / 128));  // 64 * 8 = 512
  for (int blk = 0; blk < NBLOCKS; ++blk) {
    const int li = blk * 3;
    const size_t w0 = (size_t)li * DIM * DIM;
    const size_t w1 = (size_t)(li + 1) * DIM * DIM;
    const size_t w2 = (size_t)(li + 2) * DIM * DIM;

    gemm2_kernel<true><<<ggrid, 256, 0, stream>>>(
        X0, WHI + w0, WLO + w0, bias + (size_t)li * DIM, X1, nullptr, nullptr);
    gemm2_kernel<true><<<ggrid, 256, 0, stream>>>(
        X1, WHI + w1, WLO + w1, bias + (size_t)(li + 1) * DIM, X0, nullptr, nullptr);
    const float* hin = (blk == 0) ? x : Hb;
    float* sout = (blk == NBLOCKS - 1) ? out : Sb;
    gemm2_kernel<false><<<ggrid, 256, 0, stream>>>(
        X0, WHI + w2, WLO + w2, bias + (size_t)(li + 2) * DIM, nullptr, hin, sout);
    if (blk < NBLOCKS - 1) {
      ln_kernel<<<BATCH, 256, 0, stream>>>(Sb, lnw + (size_t)blk * DIM,
                                           lnb + (size_t)blk * DIM, Hb, X0);
    }
  }
}